// Round 8
// baseline (84.161 us; speedup 1.0000x reference)
//
#include <hip/hip_runtime.h>
#include <math.h>

// ParabolicPool2D: morphological dilation (max-plus pool), KS=7, STRIDE=2, pad=3.
// Separable in max-plus: h[c,ki,kj] = g[c,ki] + g[c,kj], g[c,j] = -z_j^2/(4 t_c),
// z = linspace(-2, 3, 7)  =>  out = max_ki( max_kj(f + g_kj) + g_ki ).
//
// R8 = R7 geometry x R5 load mechanism.
//  - One WAVE owns a 112-col x TH=16-row output strip (lane L -> output cols
//    {2L, 2L+1}; lanes 56..63 masked). Row overfetch stays 37/32 = 1.156x.
//  - Horizontal halo via 3 OVERLAPPING aligned float4 loads per lane
//    (cols 4L-4..4L+11) instead of R7's 1 load + 5 ds_bpermute shuffles:
//    R7 measured only 5.4 TB/s effective — the per-row vmcnt->bpermute->
//    lgkmcnt chain throttled issue. R5's shuffle-free multi-load stream hit
//    5.84 TB/s. Overlap between the 3 loads is same-wave/same-line -> L1 hits;
//    unique HBM bytes/row ~928 B (+3.6%). Zero LDS ops remain in the kernel.

#define KS     7
#define C_CH   96
#define B_SZ   16
#define H_IN   224
#define W_IN   224
#define H_OUT  112
#define W_OUT  112
#define TH     16                    // output rows per wave-strip
#define KYV    (H_OUT / TH)          // 7 strips per plane
#define NROWS  (2 * TH + 5)          // 37 input rows per strip
#define NWAVES (B_SZ * C_CH * KYV)   // 10,752 waves

__global__ __launch_bounds__(256)
void parab_pool2d_kernel(const float* __restrict__ f,
                         const float* __restrict__ t,
                         float* __restrict__ out)
{
    const int lane = threadIdx.x & 63;
    const int wave = blockIdx.x * 4 + (threadIdx.x >> 6);

    const int tyv  = wave % KYV;
    const int rest = wave / KYV;
    const int c    = rest % C_CH;
    const int b    = rest / C_CH;

    // g[j] = -z_j^2 / (4 t_c),  z = -2 + j*(5/6)
    const float s = 1.0f / (4.0f * t[c]);
    float g[KS];
#pragma unroll
    for (int j = 0; j < KS; ++j) {
        const float z = -2.0f + (float)j * (5.0f / 6.0f);
        g[j] = -(z * z) * s;
    }

    const int ho0   = tyv * TH;
    const int ibase = 2 * ho0 - 3;            // rows [ibase, ibase+36]

    const bool active = (lane < 56);
    const bool l0     = (lane == 0);          // cols 4L-4..4L-1 OOB -> A = -inf
    const bool l55    = (lane == 55);         // cols 4L+4..4L+7 OOB -> Cv = -inf
    const int  colL   = active ? 4 * lane : 16;   // safe interior for masked lanes

    const int offA = l0  ? 0 : -4;            // clamped, aligned, in-bounds
    const int offC = l55 ? 0 :  4;

    const float  NEG = -INFINITY;
    const float4 N4  = make_float4(NEG, NEG, NEG, NEG);

    const float* __restrict__ plane = f + (b * C_CH + c) * (H_IN * W_IN);
    float* __restrict__ obase =
        out + ((b * C_CH + c) * H_OUT + ho0) * W_OUT + 2 * lane;

    float acc[TH][2];
#pragma unroll
    for (int d = 0; d < TH; ++d) { acc[d][0] = NEG; acc[d][1] = NEG; }

#pragma unroll
    for (int r = 0; r < NROWS; ++r) {          // fully unrolled, static indexing
        const int  i     = ibase + r;
        const bool rowok = (i >= 0) && (i < H_IN);
        const int  isafe = rowok ? i : 0;
        const float* rb  = plane + isafe * W_IN + colL;

        // Three independent vmcnt loads, no cross-lane ops on the chain.
        float4 A  = *(const float4*)(rb + offA);   // cols 4L-4 .. 4L-1
        float4 Bv = *(const float4*)(rb);          // cols 4L   .. 4L+3
        float4 Cv = *(const float4*)(rb + offC);   // cols 4L+4 .. 4L+7
        if (l0)  A  = N4;                          // cndmask fixups
        if (l55) Cv = N4;

        // rm0: output col 2L   <- input cols 4L-3 .. 4L+3
        float rm0 =        A.y  + g[0];
        rm0 = fmaxf(rm0,   A.z  + g[1]);
        rm0 = fmaxf(rm0,   A.w  + g[2]);
        rm0 = fmaxf(rm0,   Bv.x + g[3]);
        rm0 = fmaxf(rm0,   Bv.y + g[4]);
        rm0 = fmaxf(rm0,   Bv.z + g[5]);
        rm0 = fmaxf(rm0,   Bv.w + g[6]);
        // rm1: output col 2L+1 <- input cols 4L-1 .. 4L+5
        float rm1 =        A.w  + g[0];
        rm1 = fmaxf(rm1,   Bv.x + g[1]);
        rm1 = fmaxf(rm1,   Bv.y + g[2]);
        rm1 = fmaxf(rm1,   Bv.z + g[3]);
        rm1 = fmaxf(rm1,   Bv.w + g[4]);
        rm1 = fmaxf(rm1,   Cv.x + g[5]);
        rm1 = fmaxf(rm1,   Cv.y + g[6]);
        if (!rowok) { rm0 = NEG; rm1 = NEG; }  // -inf row: updates are no-ops

        // Vertical rolling update: output row d uses ki = r - 2d in [0,6]
        // (at most 4 rows live at any r -> acc liveness doesn't grow with TH).
#pragma unroll
        for (int d = 0; d < TH; ++d) {
            if (r >= 2 * d && r <= 2 * d + 6) {
                acc[d][0] = fmaxf(acc[d][0], rm0 + g[r - 2 * d]);
                acc[d][1] = fmaxf(acc[d][1], rm1 + g[r - 2 * d]);
            }
        }

        // Row d completes at r = 2d+6 -> emit, freeing its registers.
        if (r >= 6 && ((r - 6) & 1) == 0) {
            const int d = (r - 6) / 2;         // compile-time after unroll
            if (active)
                *(float2*)(obase + d * W_OUT) = make_float2(acc[d][0], acc[d][1]);
        }
    }
}

extern "C" void kernel_launch(void* const* d_in, const int* in_sizes, int n_in,
                              void* d_out, int out_size, void* d_ws, size_t ws_size,
                              hipStream_t stream) {
    const float* f = (const float*)d_in[0];   // [16, 96, 224, 224] f32
    const float* t = (const float*)d_in[1];   // [96] f32
    float* out = (float*)d_out;               // [16, 96, 112, 112] f32

    const int threads = 256;                  // 4 waves per block
    const int blocks  = NWAVES / 4;           // 2688, exact
    parab_pool2d_kernel<<<blocks, threads, 0, stream>>>(f, t, out);
}

// Round 9
// 80.353 us; speedup vs baseline: 1.0474x; 1.0474x over previous
//
#include <hip/hip_runtime.h>
#include <math.h>

// ParabolicPool2D: morphological dilation (max-plus pool), KS=7, STRIDE=2, pad=3.
// Separable in max-plus: h[c,ki,kj] = g[c,ki] + g[c,kj], g[c,j] = -z_j^2/(4 t_c),
// z = linspace(-2, 3, 7)  =>  out = max_ki( max_kj(f + g_kj) + g_ki ).
//
// R9 = R7 + forced 8-waves/SIMD occupancy (VGPR <= 64) + 3-shuffle halo.
//  - R5/R7/R8 all plateaued at 80-84us with eff. BW 5.3-5.8 TB/s: deep unrolled
//    bodies let the compiler hoist into the 65-128 VGPR band -> 4 waves/SIMD
//    -> thin latency-hiding margin. __launch_bounds__(256,8) pins VGPR=64 ->
//    32 waves/CU resident; TLP hides HBM+shuffle latency instead of ILP.
//  - Cross-lane halo shrunk to 3 shuffles/row by pre-reducing with wave-uniform
//    weights BEFORE the shuffle (shfl(v)+g == shfl(v+g) since g uniform per wave):
//      u = max(o.y+g0, o.z+g1, o.w+g2)  -> right neighbor's rm0 left-halo
//      t = o.w+g0                       -> right neighbor's rm1 left-halo
//      w = max(o.x+g5, o.y+g6)          -> left  neighbor's rm1 right-halo
//    Live state ~40 VGPR (only 4 acc rows live at any r), so 64 fits w/o spill.
//  - Geometry as R7: one wave = 112-col x TH=16-row strip, lane L -> out cols
//    {2L,2L+1}, lanes 56..63 masked; 1 dense float4/lane/row (896 B/wave/row);
//    row overfetch 37/32 = 1.156x; 10752 waves = 10.5/SIMD demanded.

#define KS     7
#define C_CH   96
#define B_SZ   16
#define H_IN   224
#define W_IN   224
#define H_OUT  112
#define W_OUT  112
#define TH     16                    // output rows per wave-strip
#define KYV    (H_OUT / TH)          // 7 strips per plane
#define NROWS  (2 * TH + 5)          // 37 input rows per strip
#define NWAVES (B_SZ * C_CH * KYV)   // 10,752 waves

__global__ __launch_bounds__(256, 8)
void parab_pool2d_kernel(const float* __restrict__ f,
                         const float* __restrict__ t,
                         float* __restrict__ out)
{
    const int lane = threadIdx.x & 63;
    const int wave = blockIdx.x * 4 + (threadIdx.x >> 6);

    const int tyv  = wave % KYV;
    const int rest = wave / KYV;
    const int c    = rest % C_CH;    // wave-uniform -> g[] wave-uniform
    const int b    = rest / C_CH;

    // g[j] = -z_j^2 / (4 t_c),  z = -2 + j*(5/6)
    const float s = 1.0f / (4.0f * t[c]);
    float g[KS];
#pragma unroll
    for (int j = 0; j < KS; ++j) {
        const float z = -2.0f + (float)j * (5.0f / 6.0f);
        g[j] = -(z * z) * s;
    }

    const int ho0   = tyv * TH;
    const int ibase = 2 * ho0 - 3;            // rows [ibase, ibase+36]

    const bool active = (lane < 56);
    const bool l0     = (lane == 0);          // left halo (cols<0) is -inf pad
    const bool l55    = (lane == 55);         // right halo (cols>=224) is -inf
    const int  colL   = active ? 4 * lane : 220;  // clamped safe col base

    const float NEG = -INFINITY;
    const float* __restrict__ plane = f + (b * C_CH + c) * (H_IN * W_IN);
    float* __restrict__ obase =
        out + ((b * C_CH + c) * H_OUT + ho0) * W_OUT + 2 * lane;

    float acc[TH][2];
#pragma unroll
    for (int d = 0; d < TH; ++d) { acc[d][0] = NEG; acc[d][1] = NEG; }

#pragma unroll
    for (int r = 0; r < NROWS; ++r) {          // fully unrolled, static indexing
        const int  i     = ibase + r;
        const bool rowok = (i >= 0) && (i < H_IN);
        const int  isafe = rowok ? i : 0;

        const float4 o = *(const float4*)(plane + isafe * W_IN + colL);

        // Pre-reduced halo partials (weights applied BEFORE shuffle).
        float u  = fmaxf(fmaxf(o.y + g[0], o.z + g[1]), o.w + g[2]);
        float tt = o.w + g[0];
        float w  = fmaxf(o.x + g[5], o.y + g[6]);

        float up = __shfl_up(u, 1);            // from lane L-1: cols 4L-3..4L-1
        float tp = __shfl_up(tt, 1);           // from lane L-1: col 4L-1 (g0)
        float wp = __shfl_down(w, 1);          // from lane L+1: cols 4L+4,4L+5
        if (l0)  { up = NEG; tp = NEG; }
        if (l55) { wp = NEG; }                 // lane56 holds clamped junk

        // rm0: out col 2L   <- cols 4L-3..4L+3, g0..g6
        float rm0 = fmaxf(fmaxf(up, fmaxf(o.x + g[3], o.y + g[4])),
                          fmaxf(o.z + g[5], o.w + g[6]));
        // rm1: out col 2L+1 <- cols 4L-1..4L+5, g0..g6
        float rm1 = fmaxf(fmaxf(tp, fmaxf(o.x + g[1], o.y + g[2])),
                          fmaxf(fmaxf(o.z + g[3], o.w + g[4]), wp));
        if (!rowok) { rm0 = NEG; rm1 = NEG; }  // -inf row: updates are no-ops

        // Vertical rolling update: out row d uses ki = r - 2d in [0,6]
        // (at most 4 acc rows live at any r).
#pragma unroll
        for (int d = 0; d < TH; ++d) {
            if (r >= 2 * d && r <= 2 * d + 6) {
                acc[d][0] = fmaxf(acc[d][0], rm0 + g[r - 2 * d]);
                acc[d][1] = fmaxf(acc[d][1], rm1 + g[r - 2 * d]);
            }
        }

        // Row d completes at r = 2d+6 -> emit, freeing its registers.
        if (r >= 6 && ((r - 6) & 1) == 0) {
            const int d = (r - 6) / 2;         // compile-time after unroll
            if (active)
                *(float2*)(obase + d * W_OUT) = make_float2(acc[d][0], acc[d][1]);
        }
    }
}

extern "C" void kernel_launch(void* const* d_in, const int* in_sizes, int n_in,
                              void* d_out, int out_size, void* d_ws, size_t ws_size,
                              hipStream_t stream) {
    const float* f = (const float*)d_in[0];   // [16, 96, 224, 224] f32
    const float* t = (const float*)d_in[1];   // [96] f32
    float* out = (float*)d_out;               // [16, 96, 112, 112] f32

    const int threads = 256;                  // 4 waves per block
    const int blocks  = NWAVES / 4;           // 2688, exact
    parab_pool2d_kernel<<<blocks, threads, 0, stream>>>(f, t, out);
}